// Round 8
// baseline (438.903 us; speedup 1.0000x reference)
//
#include <hip/hip_runtime.h>
#include <stdint.h>

typedef unsigned short ushort_t;
typedef __attribute__((ext_vector_type(8))) short bf16x8;   // 8 bf16 = 4 VGPRs
typedef __attribute__((ext_vector_type(4))) float f32x4;

__device__ __forceinline__ ushort_t f2bf(float f) {
  union { float f; uint32_t u; } v; v.f = f;
  uint32_t u = v.u;
  u += 0x7FFFu + ((u >> 16) & 1u);   // RNE
  return (ushort_t)(u >> 16);
}
__device__ __forceinline__ float bf2f(ushort_t h) {
  union { uint32_t u; float f; } v; v.u = ((uint32_t)h) << 16;
  return v.f;
}
__device__ __forceinline__ void gl2lds16(const void* g, void* l) {
  __builtin_amdgcn_global_load_lds(
      (__attribute__((address_space(1))) void*)(uintptr_t)g,
      (__attribute__((address_space(3))) void*)(uint32_t)(uintptr_t)l,
      16, 0, 0);
}

// ==================== ALGEBRAIC RESTRUCTURE (R8) ====================
// kv = K^T V = Wk^T (Xr^T Xi) Wv.  Pipeline:
//   prep2: W transposes (bf16) + X fp32->bf16 straight (d_out) AND transposed (ws)
//   gq   : Q = (Xr@Wqr) .* (Xi@Wqi)   dual-acc 256x128 GEMM, gate in f32 regs
//   gpart: G-partials fp32 = Xr^T Xi  (split-K over n, 16 z-slices) -> d_out
//   g_reduce: fp32 partials -> G bf16 [4][1024][1024]
//   gemm1k x2: H = Wv^T G ; KVT = H Wk^T  (per-batch 1024^3)
//   fin  : Out = Q @ KVT^T  (unchanged)
// GEMM total 155 GF (was 206); K^T/V^T epilogues, KT/VT/KVP traffic, QR
// round-trip all eliminated (~250 MB HBM saved).
// All K-loops use the R7-verified skeleton: per tile { vmcnt(0)+lgkm(0)+barrier;
// prefetch next tile; read frags; MFMA }, chunk-XOR swizzle kg = chunk ^ ((row>>1)&3)
// (conflict-free per R7 counter), tail-safe conditional prefetch.

// ---------- 256x128, BK=32, 8-wave single GEMM (gpart / fin) ----------
template <bool F32OUT>
__device__ __forceinline__ void gemm256x128(
    const ushort_t* __restrict__ A, int lda,
    const ushort_t* __restrict__ Bt, int ldb,
    int m0, int n0, int K, char* __restrict__ smem,
    f32x4 (&acc)[4][4]) {
  const int t = threadIdx.x;
  const int nt = K >> 5;
  const int rowS = t >> 2;
  const int kgS = (t & 3) ^ ((t >> 3) & 3);
  const ushort_t* a0 = A + (size_t)(m0 + rowS) * lda + kgS * 8;
  const ushort_t* a1 = a0 + (size_t)128 * lda;
  const ushort_t* b0 = Bt + (size_t)(n0 + rowS) * ldb + kgS * 8;
  const int d0 = t * 16;
  const int lane = t & 63, wid = t >> 6;
  const int wm = wid >> 1, wn = wid & 1;
  const int lr = lane & 15, lq = lane >> 4;
  const int o = lr * 64 + ((lq ^ ((lr >> 1) & 3)) << 4);
  const int aW = wm * 4096;
  const int bW = 16384 + wn * 4096;

#define STAGE(tt, buf) do { \
    char* s = smem + (buf); \
    gl2lds16(a0 + (tt) * 32, s + d0); \
    gl2lds16(a1 + (tt) * 32, s + 8192 + d0); \
    gl2lds16(b0 + (tt) * 32, s + 16384 + d0); \
  } while (0)

  bf16x8 aF[4], bF[4];
  STAGE(0, 0);
  for (int tt = 0; tt < nt; ++tt) {
    asm volatile("s_waitcnt vmcnt(0) lgkmcnt(0)\n\ts_barrier" ::: "memory");
    const int cb = (tt & 1) ? 24576 : 0;
    if (tt + 1 < nt) STAGE(tt + 1, (tt & 1) ? 0 : 24576);
    const char* base = smem + cb;
    #pragma unroll
    for (int mi = 0; mi < 4; ++mi)
      aF[mi] = *(const bf16x8*)(base + aW + mi * 1024 + o);
    #pragma unroll
    for (int ni = 0; ni < 4; ++ni)
      bF[ni] = *(const bf16x8*)(base + bW + ni * 1024 + o);
    __builtin_amdgcn_s_setprio(1);
    #pragma unroll
    for (int mi = 0; mi < 4; ++mi)
      #pragma unroll
      for (int ni = 0; ni < 4; ++ni)
        acc[mi][ni] = __builtin_amdgcn_mfma_f32_16x16x32_bf16(aF[mi], bF[ni], acc[mi][ni], 0, 0, 0);
    __builtin_amdgcn_s_setprio(0);
  }
#undef STAGE
}

// ---- gq: Q = (Xr@WtQR^T) .* (Xi@WtQI^T), 256x128 tile, dual accumulators ----
// LDS: Ar 16K | Ai 16K | Br 8K | Bi 8K per buf (48K), dbuf = 96KB.
__global__ __launch_bounds__(512, 2) void gq(
    const ushort_t* __restrict__ Xr, const ushort_t* __restrict__ Xi,
    const ushort_t* __restrict__ Wr, const ushort_t* __restrict__ Wi,
    ushort_t* __restrict__ Q) {
  extern __shared__ char smem[];
  const int bid = blockIdx.x;
  const int xcd = bid & 7, i = bid >> 3;
  const int m0 = (xcd * 8 + (i >> 3)) * 256;
  const int n0 = (i & 7) * 128;
  const int t = threadIdx.x;
  const int lane = t & 63, wid = t >> 6;
  const int wm = wid >> 1, wn = wid & 1;
  const int lr = lane & 15, lq = lane >> 4;

  const int rowS = t >> 2;
  const int kgS = (t & 3) ^ ((t >> 3) & 3);
  const ushort_t* ar0 = Xr + (size_t)(m0 + rowS) * 1024 + kgS * 8;
  const ushort_t* ar1 = ar0 + (size_t)128 * 1024;
  const ushort_t* ai0 = Xi + (size_t)(m0 + rowS) * 1024 + kgS * 8;
  const ushort_t* ai1 = ai0 + (size_t)128 * 1024;
  const ushort_t* br0 = Wr + (size_t)(n0 + rowS) * 1024 + kgS * 8;
  const ushort_t* bi0 = Wi + (size_t)(n0 + rowS) * 1024 + kgS * 8;
  const int d0 = t * 16;
  const int o = lr * 64 + ((lq ^ ((lr >> 1) & 3)) << 4);
  const int aW = wm * 4096;
  const int bW = wn * 4096;

#define STAGEQ(tt, buf) do { \
    char* s = smem + (buf); \
    gl2lds16(ar0 + (tt) * 32, s + d0); \
    gl2lds16(ar1 + (tt) * 32, s + 8192 + d0); \
    gl2lds16(ai0 + (tt) * 32, s + 16384 + d0); \
    gl2lds16(ai1 + (tt) * 32, s + 24576 + d0); \
    gl2lds16(br0 + (tt) * 32, s + 32768 + d0); \
    gl2lds16(bi0 + (tt) * 32, s + 40960 + d0); \
  } while (0)

  f32x4 accR[4][4] = {}, accI[4][4] = {};
  bf16x8 aR[4], aI[4], bR[4], bI[4];

  STAGEQ(0, 0);
  for (int tt = 0; tt < 32; ++tt) {
    asm volatile("s_waitcnt vmcnt(0) lgkmcnt(0)\n\ts_barrier" ::: "memory");
    const int cb = (tt & 1) ? 49152 : 0;
    if (tt + 1 < 32) STAGEQ(tt + 1, (tt & 1) ? 0 : 49152);
    const char* base = smem + cb;
    #pragma unroll
    for (int mi = 0; mi < 4; ++mi) {
      aR[mi] = *(const bf16x8*)(base + aW + mi * 1024 + o);
      aI[mi] = *(const bf16x8*)(base + 16384 + aW + mi * 1024 + o);
    }
    #pragma unroll
    for (int ni = 0; ni < 4; ++ni) {
      bR[ni] = *(const bf16x8*)(base + 32768 + bW + ni * 1024 + o);
      bI[ni] = *(const bf16x8*)(base + 40960 + bW + ni * 1024 + o);
    }
    __builtin_amdgcn_s_setprio(1);
    #pragma unroll
    for (int mi = 0; mi < 4; ++mi)
      #pragma unroll
      for (int ni = 0; ni < 4; ++ni) {
        accR[mi][ni] = __builtin_amdgcn_mfma_f32_16x16x32_bf16(aR[mi], bR[ni], accR[mi][ni], 0, 0, 0);
        accI[mi][ni] = __builtin_amdgcn_mfma_f32_16x16x32_bf16(aI[mi], bI[ni], accI[mi][ni], 0, 0, 0);
      }
    __builtin_amdgcn_s_setprio(0);
  }
#undef STAGEQ

  #pragma unroll
  for (int mi = 0; mi < 4; ++mi) {
    int rbase = m0 + wm * 64 + mi * 16 + lq * 4;
    #pragma unroll
    for (int ni = 0; ni < 4; ++ni) {
      int c = n0 + wn * 64 + ni * 16 + lr;
      #pragma unroll
      for (int r = 0; r < 4; ++r)
        Q[(size_t)(rbase + r) * 1024 + c] = f2bf(accR[mi][ni][r] * accI[mi][ni][r]);
    }
  }
}

// ---- gpart: fp32 partials of G = Xr^T Xi, split-K over n (16 z), grid 512 ----
__global__ __launch_bounds__(512, 4) void gpart(
    const ushort_t* __restrict__ XrT, const ushort_t* __restrict__ XiT,
    float* __restrict__ P) {
  extern __shared__ char smem[];
  const int bid = blockIdx.x;
  const int xcd = bid & 7, i = bid >> 3;        // i: 0..63
  const int z = xcd * 2 + (i >> 5);
  const int mn = i & 31;
  const int m0 = (mn >> 3) * 256, n0 = (mn & 7) * 128;
  const int b = z & 3, s = z >> 2;
  const ushort_t* A = XrT + ((size_t)b << 22) + s * 1024;
  const ushort_t* Bt = XiT + ((size_t)b << 22) + s * 1024;
  f32x4 acc[4][4] = {};
  gemm256x128<true>(A, 4096, Bt, 4096, m0, n0, 1024, smem, acc);

  const int t = threadIdx.x, lane = t & 63, wid = t >> 6;
  const int wm = wid >> 1, wn = wid & 1;
  const int lr = lane & 15, lq = lane >> 4;
  float* C = P + ((size_t)z << 20);
  #pragma unroll
  for (int mi = 0; mi < 4; ++mi) {
    int rbase = m0 + wm * 64 + mi * 16 + lq * 4;
    #pragma unroll
    for (int ni = 0; ni < 4; ++ni) {
      int c = n0 + wn * 64 + ni * 16 + lr;
      #pragma unroll
      for (int r = 0; r < 4; ++r)
        C[(size_t)(rbase + r) * 1024 + c] = acc[mi][ni][r];
    }
  }
}

__global__ __launch_bounds__(256) void g_reduce(const float* __restrict__ P,
                                                ushort_t* __restrict__ G) {
  size_t e4 = ((size_t)blockIdx.x * 256 + threadIdx.x) * 4;  // < 4M
  int b = (int)(e4 >> 20);
  size_t j = e4 & ((1u << 20) - 1);
  float s0 = 0.f, s1 = 0.f, s2 = 0.f, s3 = 0.f;
  #pragma unroll
  for (int sp = 0; sp < 4; ++sp) {
    float4 v = *(const float4*)(P + ((size_t)(sp * 4 + b) << 20) + j);
    s0 += v.x; s1 += v.y; s2 += v.z; s3 += v.w;
  }
  *(ushort4*)&G[e4] = make_ushort4(f2bf(s0), f2bf(s1), f2bf(s2), f2bf(s3));
}

// ---- gemm1k: per-batch C[1024][1024] = A @ Bt^T, 128x128 tile, 4 waves ----
// aStride/btStride = per-batch element strides (0 = shared operand).
__global__ __launch_bounds__(256, 4) void gemm1k(
    const ushort_t* __restrict__ Abase, int aStride,
    const ushort_t* __restrict__ Btbase, int btStride,
    ushort_t* __restrict__ Cbase) {
  extern __shared__ char smem[];
  const int bid = blockIdx.x;
  const int b = bid >> 6, mn = bid & 63;
  const int m0 = (mn >> 3) * 128, n0 = (mn & 7) * 128;
  const ushort_t* A = Abase + (size_t)b * (size_t)aStride;
  const ushort_t* Bt = Btbase + (size_t)b * (size_t)btStride;

  const int t = threadIdx.x;
  const int lane = t & 63, wid = t >> 6;
  const int wm = wid >> 1, wn = wid & 1;
  const int lr = lane & 15, lq = lane >> 4;
  const int rowS = t >> 2;
  const int kgS = (t & 3) ^ ((t >> 3) & 3);
  const ushort_t* a0 = A + (size_t)(m0 + rowS) * 1024 + kgS * 8;
  const ushort_t* a1 = a0 + (size_t)64 * 1024;
  const ushort_t* b0 = Bt + (size_t)(n0 + rowS) * 1024 + kgS * 8;
  const ushort_t* b1 = b0 + (size_t)64 * 1024;
  const int d0 = t * 16, d1 = 4096 + t * 16;
  const int o = lr * 64 + ((lq ^ ((lr >> 1) & 3)) << 4);
  const int aW = wm * 4096;
  const int bW = 8192 + wn * 4096;

#define STG1(tt, buf) do { \
    char* s = smem + (buf); \
    gl2lds16(a0 + (tt) * 32, s + d0); \
    gl2lds16(a1 + (tt) * 32, s + d1); \
    gl2lds16(b0 + (tt) * 32, s + 8192 + d0); \
    gl2lds16(b1 + (tt) * 32, s + 8192 + d1); \
  } while (0)

  f32x4 acc[4][4] = {};
  bf16x8 aF[4], bF[4];
  STG1(0, 0);
  for (int tt = 0; tt < 32; ++tt) {
    asm volatile("s_waitcnt vmcnt(0) lgkmcnt(0)\n\ts_barrier" ::: "memory");
    const int cb = (tt & 1) ? 16384 : 0;
    if (tt + 1 < 32) STG1(tt + 1, (tt & 1) ? 0 : 16384);
    const char* base = smem + cb;
    #pragma unroll
    for (int mi = 0; mi < 4; ++mi)
      aF[mi] = *(const bf16x8*)(base + aW + mi * 1024 + o);
    #pragma unroll
    for (int ni = 0; ni < 4; ++ni)
      bF[ni] = *(const bf16x8*)(base + bW + ni * 1024 + o);
    __builtin_amdgcn_s_setprio(1);
    #pragma unroll
    for (int mi = 0; mi < 4; ++mi)
      #pragma unroll
      for (int ni = 0; ni < 4; ++ni)
        acc[mi][ni] = __builtin_amdgcn_mfma_f32_16x16x32_bf16(aF[mi], bF[ni], acc[mi][ni], 0, 0, 0);
    __builtin_amdgcn_s_setprio(0);
  }
#undef STG1

  ushort_t* C = Cbase + ((size_t)b << 20);
  #pragma unroll
  for (int mi = 0; mi < 4; ++mi) {
    int rbase = m0 + wm * 64 + mi * 16 + lq * 4;
    #pragma unroll
    for (int ni = 0; ni < 4; ++ni) {
      int c = n0 + wn * 64 + ni * 16 + lr;
      #pragma unroll
      for (int r = 0; r < 4; ++r)
        C[(size_t)(rbase + r) * 1024 + c] = f2bf(acc[mi][ni][r]);
    }
  }
}

// ---- fin: Out[n][e] = sum_d Q[n][d] * KVT[b][e][d], fp32 out, grid 512 ----
__global__ __launch_bounds__(512, 4) void fin8(
    const ushort_t* __restrict__ Q, const ushort_t* __restrict__ KVT,
    float* __restrict__ Out) {
  extern __shared__ char smem[];
  const int bid = blockIdx.x;
  const int xcd = bid & 7, i = bid >> 3;        // i: 0..63
  const int m0 = (xcd * 8 + (i >> 3)) * 256;
  const int n0 = (i & 7) * 128;
  const int b = m0 >> 12;
  f32x4 acc[4][4] = {};
  gemm256x128<true>(Q, 1024, KVT + ((size_t)b << 20), 1024, m0, n0, 1024, smem, acc);

  const int t = threadIdx.x, lane = t & 63, wid = t >> 6;
  const int wm = wid >> 1, wn = wid & 1;
  const int lr = lane & 15, lq = lane >> 4;
  #pragma unroll
  for (int mi = 0; mi < 4; ++mi) {
    int rbase = m0 + wm * 64 + mi * 16 + lq * 4;
    #pragma unroll
    for (int ni = 0; ni < 4; ++ni) {
      int c = n0 + wn * 64 + ni * 16 + lr;
      #pragma unroll
      for (int r = 0; r < 4; ++r)
        Out[(size_t)(rbase + r) * 1024 + c] = acc[mi][ni][r];
    }
  }
}

// ---- prep2: weight transposes + X fp32->bf16 straight AND transposed ----
__global__ __launch_bounds__(256) void prep2(
    const float* __restrict__ xr, const float* __restrict__ xi,
    const float* w0, const float* w1, const float* w2, const float* w3,
    ushort_t* __restrict__ xrb, ushort_t* __restrict__ xib,
    ushort_t* __restrict__ xrT, ushort_t* __restrict__ xiT,
    ushort_t* o0, ushort_t* o1, ushort_t* o2, ushort_t* o3) {
  const int bid = blockIdx.x;
  const int t = threadIdx.x;
  __shared__ float tile[32][33];
  const int tx = t & 31, ty = t >> 5;   // (32, 8)
  if (bid < 4096) {
    const float* W; ushort_t* O;
    switch (bid >> 10) {
      case 0: W = w0; O = o0; break;
      case 1: W = w1; O = o1; break;
      case 2: W = w2; O = o2; break;
      default: W = w3; O = o3; break;
    }
    const int within = bid & 1023;
    const int bx = (within & 31) * 32, by = (within >> 5) * 32;
    #pragma unroll
    for (int k = 0; k < 32; k += 8)
      tile[ty + k][tx] = W[(size_t)(by + ty + k) * 1024 + bx + tx];
    __syncthreads();
    #pragma unroll
    for (int k = 0; k < 32; k += 8)
      O[(size_t)(bx + ty + k) * 1024 + by + tx] = f2bf(tile[tx][ty + k]);
  } else {
    const int xb = bid - 4096;            // 0..32767
    const int tensor = xb >> 14;          // 0: real, 1: imag
    const int within = xb & 16383;
    const int by = (within >> 5) * 32;    // n row base (0..16352)
    const int bx = (within & 31) * 32;    // d col base
    const float* src = tensor ? xi : xr;
    ushort_t* dstS = tensor ? xib : xrb;
    ushort_t* dstT = tensor ? xiT : xrT;
    #pragma unroll
    for (int k = 0; k < 32; k += 8) {
      float v = src[(size_t)(by + ty + k) * 1024 + bx + tx];
      tile[ty + k][tx] = v;
      dstS[(size_t)(by + ty + k) * 1024 + bx + tx] = f2bf(v);
    }
    __syncthreads();
    const int b = by >> 12;               // batch (tiles never cross batches)
    const int nn = by & 4095;
    #pragma unroll
    for (int k = 0; k < 32; k += 8)
      dstT[((size_t)b << 22) + (size_t)(bx + ty + k) * 4096 + nn + tx] =
          f2bf(tile[tx][ty + k]);
  }
}

extern "C" void kernel_launch(void* const* d_in, const int* in_sizes, int n_in,
                              void* d_out, int out_size, void* d_ws, size_t ws_size,
                              hipStream_t stream) {
  const float* xr  = (const float*)d_in[0];
  const float* xi  = (const float*)d_in[1];
  const float* wqr = (const float*)d_in[2];
  const float* wqi = (const float*)d_in[3];
  const float* wk  = (const float*)d_in[4];
  const float* wv  = (const float*)d_in[5];

  char* ws = (char*)d_ws;
  const size_t MB = 1024ull * 1024ull;
  ushort_t* WtQR = (ushort_t*)(ws + 0 * MB);    // Wqr^T [1024e][1024d]
  ushort_t* WtQI = (ushort_t*)(ws + 2 * MB);    // Wqi^T
  ushort_t* WtK  = (ushort_t*)(ws + 4 * MB);    // Wk^T  [d][d']
  ushort_t* WtV  = (ushort_t*)(ws + 6 * MB);    // Wv^T  [e][j]
  ushort_t* XrT  = (ushort_t*)(ws + 8 * MB);    // [4][1024d][4096n]; dead after gpart
  ushort_t* XiT  = (ushort_t*)(ws + 40 * MB);   // [4][1024e][4096n]; dead after gpart
  ushort_t* Q    = (ushort_t*)(ws + 72 * MB);   // gated query bf16 [16384][1024]
  ushort_t* G    = (ushort_t*)(ws + 104 * MB);  // [4][1024d][1024e] bf16 8MB
  ushort_t* H    = (ushort_t*)(ws + 8 * MB);    // [4][1024e][1024d'] overlay XrT
  ushort_t* KVT  = (ushort_t*)(ws + 16 * MB);   // [4][1024e][1024d] overlay XrT
  ushort_t* Xrb  = (ushort_t*)d_out;            // bf16 [16384][1024] (phase 1)
  ushort_t* Xib  = (ushort_t*)((char*)d_out + 32 * MB);
  float*    Pf   = (float*)d_out;               // fp32 G-partials [16][1M] (phase 2)

  static bool inited = false;
  if (!inited) {
    inited = true;
    hipFuncSetAttribute((const void*)&gq,     hipFuncAttributeMaxDynamicSharedMemorySize, 98304);
    hipFuncSetAttribute((const void*)&gpart,  hipFuncAttributeMaxDynamicSharedMemorySize, 49152);
    hipFuncSetAttribute((const void*)&gemm1k, hipFuncAttributeMaxDynamicSharedMemorySize, 32768);
    hipFuncSetAttribute((const void*)&fin8,   hipFuncAttributeMaxDynamicSharedMemorySize, 49152);
  }

  prep2<<<36864, 256, 0, stream>>>(xr, xi, wqr, wqi, wk, wv,
                                   Xrb, Xib, XrT, XiT, WtQR, WtQI, WtK, WtV);
  gq<<<512, 512, 98304, stream>>>(Xrb, Xib, WtQR, WtQI, Q);      // consumes d_out Xb
  gpart<<<512, 512, 49152, stream>>>(XrT, XiT, Pf);              // writes d_out fp32
  g_reduce<<<4096, 256, 0, stream>>>(Pf, G);
  gemm1k<<<256, 256, 32768, stream>>>(WtV, 0, G, 1 << 20, H);    // H = Wv^T G
  gemm1k<<<256, 256, 32768, stream>>>(H, 1 << 20, WtK, 0, KVT);  // KVT = H Wk^T
  fin8<<<512, 512, 49152, stream>>>(Q, KVT, (float*)d_out);
}

// Round 10
// 423.952 us; speedup vs baseline: 1.0353x; 1.0353x over previous
//
#include <hip/hip_runtime.h>
#include <stdint.h>

typedef unsigned short ushort_t;
typedef __attribute__((ext_vector_type(8))) short bf16x8;   // 8 bf16 = 4 VGPRs
typedef __attribute__((ext_vector_type(4))) float f32x4;

__device__ __forceinline__ ushort_t f2bf(float f) {
  union { float f; uint32_t u; } v; v.f = f;
  uint32_t u = v.u;
  u += 0x7FFFu + ((u >> 16) & 1u);   // RNE
  return (ushort_t)(u >> 16);
}
__device__ __forceinline__ float bf2f(ushort_t h) {
  union { uint32_t u; float f; } v; v.u = ((uint32_t)h) << 16;
  return v.f;
}
__device__ __forceinline__ void gl2lds16(const void* g, void* l) {
  __builtin_amdgcn_global_load_lds(
      (__attribute__((address_space(1))) void*)(uintptr_t)g,
      (__attribute__((address_space(3))) void*)(uint32_t)(uintptr_t)l,
      16, 0, 0);
}

// Pipeline (R8 algebra, R9 implementation fixes; R10 = infra retry of R9):
//   kv = K^T V = Wk^T (Xr^T Xi) Wv
//   prep2: W^T (bf16) + X fp32->bf16 straight AND transposed, all wide-IO
//   gq   : Q = (Xr@Wqr) .* (Xi@Wqi), 48KB alternating R/I dbuf (2 blocks/CU)
//   gpart: bf16 partials of G = Xr^T Xi (split-K 16 z)  [bf16: R3-proven]
//   g_reduce: bf16 partials -> G bf16
//   gemm1k x2: H = Wv^T G ; KVT = H Wk^T   (128x64 tiles, 2 blocks/CU)
//   fin  : Out = Q @ KVT^T
// All K-loops: R7-verified skeleton { vmcnt(0)+lgkm(0)+barrier; prefetch next;
// read frags; MFMA }, swizzle kg = chunk ^ ((row>>1)&3) (conflict-free, R7 PMC).

// ---------- 256x128, BK=32, 8-wave GEMM core (gpart / fin) ----------
__device__ __forceinline__ void gemm256x128(
    const ushort_t* __restrict__ A, int lda,
    const ushort_t* __restrict__ Bt, int ldb,
    int m0, int n0, int K, char* __restrict__ smem,
    f32x4 (&acc)[4][4]) {
  const int t = threadIdx.x;
  const int nt = K >> 5;
  const int rowS = t >> 2;
  const int kgS = (t & 3) ^ ((t >> 3) & 3);
  const ushort_t* a0 = A + (size_t)(m0 + rowS) * lda + kgS * 8;
  const ushort_t* a1 = a0 + (size_t)128 * lda;
  const ushort_t* b0 = Bt + (size_t)(n0 + rowS) * ldb + kgS * 8;
  const int d0 = t * 16;
  const int lane = t & 63, wid = t >> 6;
  const int wm = wid >> 1, wn = wid & 1;
  const int lr = lane & 15, lq = lane >> 4;
  const int o = lr * 64 + ((lq ^ ((lr >> 1) & 3)) << 4);
  const int aW = wm * 4096;
  const int bW = 16384 + wn * 4096;

#define STAGE(tt, buf) do { \
    char* s = smem + (buf); \
    gl2lds16(a0 + (tt) * 32, s + d0); \
    gl2lds16(a1 + (tt) * 32, s + 8192 + d0); \
    gl2lds16(b0 + (tt) * 32, s + 16384 + d0); \
  } while (0)

  bf16x8 aF[4], bF[4];
  STAGE(0, 0);
  for (int tt = 0; tt < nt; ++tt) {
    asm volatile("s_waitcnt vmcnt(0) lgkmcnt(0)\n\ts_barrier" ::: "memory");
    const int cb = (tt & 1) ? 24576 : 0;
    if (tt + 1 < nt) STAGE(tt + 1, (tt & 1) ? 0 : 24576);
    const char* base = smem + cb;
    #pragma unroll
    for (int mi = 0; mi < 4; ++mi)
      aF[mi] = *(const bf16x8*)(base + aW + mi * 1024 + o);
    #pragma unroll
    for (int ni = 0; ni < 4; ++ni)
      bF[ni] = *(const bf16x8*)(base + bW + ni * 1024 + o);
    __builtin_amdgcn_s_setprio(1);
    #pragma unroll
    for (int mi = 0; mi < 4; ++mi)
      #pragma unroll
      for (int ni = 0; ni < 4; ++ni)
        acc[mi][ni] = __builtin_amdgcn_mfma_f32_16x16x32_bf16(aF[mi], bF[ni], acc[mi][ni], 0, 0, 0);
    __builtin_amdgcn_s_setprio(0);
  }
#undef STAGE
}

// ---- gq: Q = (Xr@WtQR^T) .* (Xi@WtQI^T), 256x128 tile, alternating R/I ----
// 48KB LDS (2 x 24KB bufs) -> 2 blocks/CU (LDS- and VGPR-feasible; bounds
// kept at (512,2) so the dual accumulator isn't reg-capped into spills).
// Sub-step ledger (race-audited):
//   subA(ks): boundary; STG_I(ks)->buf1; read buf0; MFMA accR
//   subB(ks): boundary; STG_R(ks+1)->buf0; read buf1; MFMA accI
// Each stage targets the buffer NOT read this sub-step; boundary's lgkm(0)
// orders all reads before any overwrite, vmcnt(0) covers the staged buffer.
__global__ __launch_bounds__(512, 2) void gq(
    const ushort_t* __restrict__ Xr, const ushort_t* __restrict__ Xi,
    const ushort_t* __restrict__ Wr, const ushort_t* __restrict__ Wi,
    ushort_t* __restrict__ Q) {
  extern __shared__ char smem[];
  const int bid = blockIdx.x;
  const int xcd = bid & 7, i = bid >> 3;
  const int m0 = (xcd * 8 + (i >> 3)) * 256;
  const int n0 = (i & 7) * 128;
  const int t = threadIdx.x;
  const int lane = t & 63, wid = t >> 6;
  const int wm = wid >> 1, wn = wid & 1;
  const int lr = lane & 15, lq = lane >> 4;

  const int rowS = t >> 2;
  const int kgS = (t & 3) ^ ((t >> 3) & 3);
  const ushort_t* ar0 = Xr + (size_t)(m0 + rowS) * 1024 + kgS * 8;
  const ushort_t* ar1 = ar0 + (size_t)128 * 1024;
  const ushort_t* ai0 = Xi + (size_t)(m0 + rowS) * 1024 + kgS * 8;
  const ushort_t* ai1 = ai0 + (size_t)128 * 1024;
  const ushort_t* br0 = Wr + (size_t)(n0 + rowS) * 1024 + kgS * 8;
  const ushort_t* bi0 = Wi + (size_t)(n0 + rowS) * 1024 + kgS * 8;
  const int d0 = t * 16;
  const int o = lr * 64 + ((lq ^ ((lr >> 1) & 3)) << 4);
  const int aW = wm * 4096;
  const int bW = 16384 + wn * 4096;

#define STG3(p0, p1, pb, ks, buf) do { \
    char* s = smem + (buf); \
    gl2lds16(p0 + (ks) * 32, s + d0); \
    gl2lds16(p1 + (ks) * 32, s + 8192 + d0); \
    gl2lds16(pb + (ks) * 32, s + 16384 + d0); \
  } while (0)
#define RDFRAG(buf) do { \
    const char* base = smem + (buf); \
    _Pragma("unroll") \
    for (int mi = 0; mi < 4; ++mi) aF[mi] = *(const bf16x8*)(base + aW + mi * 1024 + o); \
    _Pragma("unroll") \
    for (int ni = 0; ni < 4; ++ni) bF[ni] = *(const bf16x8*)(base + bW + ni * 1024 + o); \
  } while (0)
#define MM(ACC) \
    __builtin_amdgcn_s_setprio(1); \
    _Pragma("unroll") \
    for (int mi = 0; mi < 4; ++mi) \
      _Pragma("unroll") \
      for (int ni = 0; ni < 4; ++ni) \
        ACC[mi][ni] = __builtin_amdgcn_mfma_f32_16x16x32_bf16(aF[mi], bF[ni], ACC[mi][ni], 0, 0, 0); \
    __builtin_amdgcn_s_setprio(0);
#define BND() asm volatile("s_waitcnt vmcnt(0) lgkmcnt(0)\n\ts_barrier" ::: "memory")

  f32x4 accR[4][4] = {}, accI[4][4] = {};
  bf16x8 aF[4], bF[4];

  STG3(ar0, ar1, br0, 0, 0);
  for (int ks = 0; ks < 32; ++ks) {
    BND();
    STG3(ai0, ai1, bi0, ks, 24576);
    RDFRAG(0);
    MM(accR)
    BND();
    if (ks + 1 < 32) STG3(ar0, ar1, br0, ks + 1, 0);
    RDFRAG(24576);
    MM(accI)
  }
#undef STG3
#undef RDFRAG
#undef MM
#undef BND

  #pragma unroll
  for (int mi = 0; mi < 4; ++mi) {
    int rbase = m0 + wm * 64 + mi * 16 + lq * 4;
    #pragma unroll
    for (int ni = 0; ni < 4; ++ni) {
      int c = n0 + wn * 64 + ni * 16 + lr;
      #pragma unroll
      for (int r = 0; r < 4; ++r)
        Q[(size_t)(rbase + r) * 1024 + c] = f2bf(accR[mi][ni][r] * accI[mi][ni][r]);
    }
  }
}

// ---- gpart: bf16 partials of G = Xr^T Xi, split-K over n (16 z), grid 512 ----
__global__ __launch_bounds__(512, 4) void gpart(
    const ushort_t* __restrict__ XrT, const ushort_t* __restrict__ XiT,
    ushort_t* __restrict__ P) {
  extern __shared__ char smem[];
  const int bid = blockIdx.x;
  const int xcd = bid & 7, i = bid >> 3;        // i: 0..63
  const int z = xcd * 2 + (i >> 5);
  const int mn = i & 31;
  const int m0 = (mn >> 3) * 256, n0 = (mn & 7) * 128;
  const int b = z & 3, s = z >> 2;
  const ushort_t* A = XrT + ((size_t)b << 22) + s * 1024;
  const ushort_t* Bt = XiT + ((size_t)b << 22) + s * 1024;
  f32x4 acc[4][4] = {};
  gemm256x128(A, 4096, Bt, 4096, m0, n0, 1024, smem, acc);

  const int t = threadIdx.x, lane = t & 63, wid = t >> 6;
  const int wm = wid >> 1, wn = wid & 1;
  const int lr = lane & 15, lq = lane >> 4;
  ushort_t* C = P + ((size_t)z << 20);
  #pragma unroll
  for (int mi = 0; mi < 4; ++mi) {
    int rbase = m0 + wm * 64 + mi * 16 + lq * 4;
    #pragma unroll
    for (int ni = 0; ni < 4; ++ni) {
      int c = n0 + wn * 64 + ni * 16 + lr;
      #pragma unroll
      for (int r = 0; r < 4; ++r)
        C[(size_t)(rbase + r) * 1024 + c] = f2bf(acc[mi][ni][r]);
    }
  }
}

__global__ __launch_bounds__(256) void g_reduce(const ushort_t* __restrict__ P,
                                                ushort_t* __restrict__ G) {
  size_t e4 = ((size_t)blockIdx.x * 256 + threadIdx.x) * 4;  // < 4M
  int b = (int)(e4 >> 20);
  size_t j = e4 & ((1u << 20) - 1);
  float s0 = 0.f, s1 = 0.f, s2 = 0.f, s3 = 0.f;
  #pragma unroll
  for (int sp = 0; sp < 4; ++sp) {
    ushort4 v = *(const ushort4*)(P + ((size_t)(sp * 4 + b) << 20) + j);
    s0 += bf2f(v.x); s1 += bf2f(v.y); s2 += bf2f(v.z); s3 += bf2f(v.w);
  }
  *(ushort4*)&G[e4] = make_ushort4(f2bf(s0), f2bf(s1), f2bf(s2), f2bf(s3));
}

// ---- gemm1k: per-batch C[1024][1024] = A @ Bt^T, 128x64 tiles, 512 blocks ----
// 2-wave blocks, 24KB LDS -> 2 blocks/CU by grid.  aStride/btStride per batch.
__global__ __launch_bounds__(128, 4) void gemm1k(
    const ushort_t* __restrict__ Abase, int aStride,
    const ushort_t* __restrict__ Btbase, int btStride,
    ushort_t* __restrict__ Cbase) {
  extern __shared__ char smem[];
  const int bid = blockIdx.x;
  const int b = bid >> 7, mn = bid & 127;
  const int m0 = (mn >> 4) * 128, n0 = (mn & 15) * 64;
  const ushort_t* A = Abase + (size_t)b * (size_t)aStride;
  const ushort_t* Bt = Btbase + (size_t)b * (size_t)btStride;

  const int t = threadIdx.x;                  // 0..127
  const int lane = t & 63, wid = t >> 6;      // 2 waves: wm = wid
  const int lr = lane & 15, lq = lane >> 4;

  // staging: A 128rowsx4chunks (4/thread), B 64rowsx4chunks (2/thread)
  const ushort_t* pa[4];
  const ushort_t* pb[2];
  int dA[4], dB[2];
  #pragma unroll
  for (int p = 0; p < 4; ++p) {
    int ch = p * 128 + t;
    int row = ch >> 2;
    int kg = (ch & 3) ^ ((row >> 1) & 3);
    pa[p] = A + (size_t)(m0 + row) * 1024 + kg * 8;
    dA[p] = ch * 16;
  }
  #pragma unroll
  for (int p = 0; p < 2; ++p) {
    int ch = p * 128 + t;
    int row = ch >> 2;
    int kg = (ch & 3) ^ ((row >> 1) & 3);
    pb[p] = Bt + (size_t)(n0 + row) * 1024 + kg * 8;
    dB[p] = 8192 + ch * 16;
  }
  const int o = lr * 64 + ((lq ^ ((lr >> 1) & 3)) << 4);
  const int aW = wid * 4096;                  // wave's 64 A-rows

#define STG1(tt, buf) do { \
    char* s = smem + (buf); \
    gl2lds16(pa[0] + (tt) * 32, s + dA[0]); \
    gl2lds16(pa[1] + (tt) * 32, s + dA[1]); \
    gl2lds16(pa[2] + (tt) * 32, s + dA[2]); \
    gl2lds16(pa[3] + (tt) * 32, s + dA[3]); \
    gl2lds16(pb[0] + (tt) * 32, s + dB[0]); \
    gl2lds16(pb[1] + (tt) * 32, s + dB[1]); \
  } while (0)

  f32x4 acc[4][4] = {};
  bf16x8 aF[4], bF[4];
  STG1(0, 0);
  for (int tt = 0; tt < 32; ++tt) {
    asm volatile("s_waitcnt vmcnt(0) lgkmcnt(0)\n\ts_barrier" ::: "memory");
    const int cb = (tt & 1) ? 12288 : 0;
    if (tt + 1 < 32) STG1(tt + 1, (tt & 1) ? 0 : 12288);
    const char* base = smem + cb;
    #pragma unroll
    for (int mi = 0; mi < 4; ++mi)
      aF[mi] = *(const bf16x8*)(base + aW + mi * 1024 + o);
    #pragma unroll
    for (int ni = 0; ni < 4; ++ni)
      bF[ni] = *(const bf16x8*)(base + 8192 + ni * 1024 + o);
    __builtin_amdgcn_s_setprio(1);
    #pragma unroll
    for (int mi = 0; mi < 4; ++mi)
      #pragma unroll
      for (int ni = 0; ni < 4; ++ni)
        acc[mi][ni] = __builtin_amdgcn_mfma_f32_16x16x32_bf16(aF[mi], bF[ni], acc[mi][ni], 0, 0, 0);
    __builtin_amdgcn_s_setprio(0);
  }
#undef STG1

  ushort_t* C = Cbase + ((size_t)b << 20);
  #pragma unroll
  for (int mi = 0; mi < 4; ++mi) {
    int rbase = m0 + wid * 64 + mi * 16 + lq * 4;
    #pragma unroll
    for (int ni = 0; ni < 4; ++ni) {
      int c = n0 + ni * 16 + lr;
      #pragma unroll
      for (int r = 0; r < 4; ++r)
        C[(size_t)(rbase + r) * 1024 + c] = f2bf(acc[mi][ni][r]);
    }
  }
}

// ---- fin: Out[n][e] = sum_d Q[n][d] * KVT[b][e][d], fp32 out, grid 512 ----
__global__ __launch_bounds__(512, 4) void fin8(
    const ushort_t* __restrict__ Q, const ushort_t* __restrict__ KVT,
    float* __restrict__ Out) {
  extern __shared__ char smem[];
  const int bid = blockIdx.x;
  const int xcd = bid & 7, i = bid >> 3;        // i: 0..63
  const int m0 = (xcd * 8 + (i >> 3)) * 256;
  const int n0 = (i & 7) * 128;
  const int b = m0 >> 12;
  f32x4 acc[4][4] = {};
  gemm256x128(Q, 1024, KVT + ((size_t)b << 20), 1024, m0, n0, 1024, smem, acc);

  const int t = threadIdx.x, lane = t & 63, wid = t >> 6;
  const int wm = wid >> 1, wn = wid & 1;
  const int lr = lane & 15, lq = lane >> 4;
  #pragma unroll
  for (int mi = 0; mi < 4; ++mi) {
    int rbase = m0 + wm * 64 + mi * 16 + lq * 4;
    #pragma unroll
    for (int ni = 0; ni < 4; ++ni) {
      int c = n0 + wn * 64 + ni * 16 + lr;
      #pragma unroll
      for (int r = 0; r < 4; ++r)
        Out[(size_t)(rbase + r) * 1024 + c] = acc[mi][ni][r];
    }
  }
}

// ---- prep2: W^T (32x32 tiles) + X one-pass straight+transposed (64x64, wide IO) ----
__global__ __launch_bounds__(256) void prep2(
    const float* __restrict__ xr, const float* __restrict__ xi,
    const float* w0, const float* w1, const float* w2, const float* w3,
    ushort_t* __restrict__ xrb, ushort_t* __restrict__ xib,
    ushort_t* __restrict__ xrT, ushort_t* __restrict__ xiT,
    ushort_t* o0, ushort_t* o1, ushort_t* o2, ushort_t* o3) {
  const int bid = blockIdx.x;
  const int t = threadIdx.x;
  if (bid < 4096) {
    __shared__ float tile[32][33];
    const int tx = t & 31, ty = t >> 5;   // (32, 8)
    const float* W; ushort_t* O;
    switch (bid >> 10) {
      case 0: W = w0; O = o0; break;
      case 1: W = w1; O = o1; break;
      case 2: W = w2; O = o2; break;
      default: W = w3; O = o3; break;
    }
    const int within = bid & 1023;
    const int bx = (within & 31) * 32, by = (within >> 5) * 32;
    #pragma unroll
    for (int k = 0; k < 32; k += 8)
      tile[ty + k][tx] = W[(size_t)(by + ty + k) * 1024 + bx + tx];
    __syncthreads();
    #pragma unroll
    for (int k = 0; k < 32; k += 8)
      O[(size_t)(bx + ty + k) * 1024 + by + tx] = f2bf(tile[tx][ty + k]);
  } else {
    __shared__ float tx64[64][65];        // +1 pad: col reads 2-way max
    const int xb = bid - 4096;            // 0..8191
    const int tensor = xb >> 12;          // 4096 tiles each
    const int within = xb & 4095;
    const int n0 = (within >> 4) * 64;    // 256 n-tiles
    const int d0g = (within & 15) * 64;   // 16 d-tiles
    const float* src = tensor ? xi : xr;
    ushort_t* dstS = tensor ? xib : xrb;
    ushort_t* dstT = tensor ? xiT : xrT;
    const int r = t >> 2;                 // 0..63
    const int c4 = (t & 3) * 4;
    #pragma unroll
    for (int p = 0; p < 4; ++p) {
      float4 v = *(const float4*)&src[(size_t)(n0 + r) * 1024 + d0g + c4 + p * 16];
      tx64[r][c4 + p * 16 + 0] = v.x;
      tx64[r][c4 + p * 16 + 1] = v.y;
      tx64[r][c4 + p * 16 + 2] = v.z;
      tx64[r][c4 + p * 16 + 3] = v.w;
    }
    __syncthreads();
    {   // straight: row r, 16 cols per thread, bf16x8 stores
      const int c0 = (t & 3) * 16;
      ushort_t tmp[16];
      #pragma unroll
      for (int j = 0; j < 16; ++j) tmp[j] = f2bf(tx64[r][c0 + j]);
      ushort_t* p = &dstS[(size_t)(n0 + r) * 1024 + d0g + c0];
      *(bf16x8*)&p[0] = *(const bf16x8*)&tmp[0];
      *(bf16x8*)&p[8] = *(const bf16x8*)&tmp[8];
    }
    {   // transposed: d-row r, 16 n per thread, bf16x8 stores
      const int nb = (t & 3) * 16;
      ushort_t tmp[16];
      #pragma unroll
      for (int j = 0; j < 16; ++j) tmp[j] = f2bf(tx64[nb + j][r]);
      const int b = n0 >> 12, nn = n0 & 4095;
      ushort_t* p = &dstT[((size_t)b << 22) + (size_t)(d0g + r) * 4096 + nn + nb];
      *(bf16x8*)&p[0] = *(const bf16x8*)&tmp[0];
      *(bf16x8*)&p[8] = *(const bf16x8*)&tmp[8];
    }
  }
}

extern "C" void kernel_launch(void* const* d_in, const int* in_sizes, int n_in,
                              void* d_out, int out_size, void* d_ws, size_t ws_size,
                              hipStream_t stream) {
  const float* xr  = (const float*)d_in[0];
  const float* xi  = (const float*)d_in[1];
  const float* wqr = (const float*)d_in[2];
  const float* wqi = (const float*)d_in[3];
  const float* wk  = (const float*)d_in[4];
  const float* wv  = (const float*)d_in[5];

  char* ws = (char*)d_ws;
  const size_t MB = 1024ull * 1024ull;
  ushort_t* WtQR = (ushort_t*)(ws + 0 * MB);    // Wqr^T [1024e][1024d]
  ushort_t* WtQI = (ushort_t*)(ws + 2 * MB);    // Wqi^T
  ushort_t* WtK  = (ushort_t*)(ws + 4 * MB);    // Wk^T  [d][d']
  ushort_t* WtV  = (ushort_t*)(ws + 6 * MB);    // Wv^T  [e][j]
  ushort_t* XrT  = (ushort_t*)(ws + 8 * MB);    // [4][1024d][4096n]; dead after gpart
  ushort_t* XiT  = (ushort_t*)(ws + 40 * MB);   // [4][1024e][4096n]; dead after gpart
  ushort_t* Q    = (ushort_t*)(ws + 72 * MB);   // gated query bf16 [16384][1024]
  ushort_t* G    = (ushort_t*)(ws + 104 * MB);  // [4][1024d][1024e] bf16 8MB
  ushort_t* H    = (ushort_t*)(ws + 8 * MB);    // [4][1024e][1024d'] overlay XrT
  ushort_t* KVT  = (ushort_t*)(ws + 16 * MB);   // [4][1024e][1024d] overlay XrT
  ushort_t* Xrb  = (ushort_t*)d_out;            // bf16 [16384][1024] (phase 1)
  ushort_t* Xib  = (ushort_t*)((char*)d_out + 32 * MB);
  ushort_t* Pb   = (ushort_t*)d_out;            // bf16 G-partials [16][1M] (phase 2)

  static bool inited = false;
  if (!inited) {
    inited = true;
    hipFuncSetAttribute((const void*)&gq,     hipFuncAttributeMaxDynamicSharedMemorySize, 49152);
    hipFuncSetAttribute((const void*)&gpart,  hipFuncAttributeMaxDynamicSharedMemorySize, 49152);
    hipFuncSetAttribute((const void*)&gemm1k, hipFuncAttributeMaxDynamicSharedMemorySize, 24576);
    hipFuncSetAttribute((const void*)&fin8,   hipFuncAttributeMaxDynamicSharedMemorySize, 49152);
  }

  prep2<<<12288, 256, 0, stream>>>(xr, xi, wqr, wqi, wk, wv,
                                   Xrb, Xib, XrT, XiT, WtQR, WtQI, WtK, WtV);
  gq<<<512, 512, 49152, stream>>>(Xrb, Xib, WtQR, WtQI, Q);      // reads d_out Xb
  gpart<<<512, 512, 49152, stream>>>(XrT, XiT, Pb);              // writes d_out bf16
  g_reduce<<<4096, 256, 0, stream>>>(Pb, G);
  gemm1k<<<512, 128, 24576, stream>>>(WtV, 0, G, 1 << 20, H);    // H = Wv^T G
  gemm1k<<<512, 128, 24576, stream>>>(H, 1 << 20, WtK, 0, KVT);  // KVT = H Wk^T
  fin8<<<512, 512, 49152, stream>>>(Q, KVT, (float*)d_out);
}